// Round 2
// baseline (283.193 us; speedup 1.0000x reference)
//
#include <hip/hip_runtime.h>

#define TD 16
#define ZD 16
#define YD 16
#define XH 8
#define DD 12
#define NSITES (TD*ZD*YD*XH)      // 32768
#define SPB 16                    // sites per block
#define THREADS (SPB*DD)          // 192
#define DIAG 4.5f
#define VSTRIDE 100               // floats; 400B rows (16B aligned), site stride = 4 banks
#define MU_STRIDE (NSITES*144)

__device__ __forceinline__ void cdot4(const float4 kr, const float4 ki,
                                      const float4 vr, const float4 vi,
                                      float& sr, float& si) {
    sr = fmaf(kr.x, vr.x, sr); sr = fmaf(-ki.x, vi.x, sr);
    si = fmaf(kr.x, vi.x, si); si = fmaf(ki.x, vr.x, si);
    sr = fmaf(kr.y, vr.y, sr); sr = fmaf(-ki.y, vi.y, sr);
    si = fmaf(kr.y, vi.y, si); si = fmaf(ki.y, vr.y, si);
    sr = fmaf(kr.z, vr.z, sr); sr = fmaf(-ki.z, vi.z, sr);
    si = fmaf(kr.z, vi.z, si); si = fmaf(ki.z, vr.z, si);
    sr = fmaf(kr.w, vr.w, sr); sr = fmaf(-ki.w, vi.w, sr);
    si = fmaf(kr.w, vi.w, si); si = fmaf(ki.w, vr.w, si);
}

// __launch_bounds__(192,4): cap 128 VGPR -> fits depth-2 pipeline (est ~110), no spill
__global__ __launch_bounds__(THREADS, 4) void hop_kernel(
    const float* __restrict__ psi_re, const float* __restrict__ psi_im,
    const float* __restrict__ K_fwd_re, const float* __restrict__ K_fwd_im,
    const float* __restrict__ K_bwd_re, const float* __restrict__ K_bwd_im,
    float* __restrict__ out_re, float* __restrict__ out_im)
{
    __shared__ float vre[SPB][VSTRIDE];
    __shared__ float vim[SPB][VSTRIDE];

    const int tid   = threadIdx.x;
    const int site0 = blockIdx.x * SPB;

    // tid decomposition: since 192 = 16*12, element e = tid + k*192 has
    // j = tid%12 (const), sc = tid/12 + 16k -> combo c = (tid/12)&7 (const),
    // site s = (tid/12)>>3 + 2k. Each thread stages one (combo, component)
    // across 8 sites.
    const int jj  = tid % 12;
    const int scb = tid / 12;      // 0..15; phase-2 local site
    const int cc  = scb & 7;       // staged combo (per-thread const)
    const int sb  = scb >> 3;      // 0 or 1

    // direction deltas for combo cc (branchless, per-thread const)
    const int dt = (cc == 0) - (cc == 1);
    const int dz = (cc == 2) - (cc == 3);
    const int dy = (cc == 4) - (cc == 5);

    // ---- staging: all 16 gather loads issued before any LDS write ----
    float tr[8], ti[8];
    int   dst[8];
    #pragma unroll
    for (int k = 0; k < 8; ++k) {
        const int s  = sb + 2 * k;
        const int sg = site0 + s;
        const int x = sg & 7, y = (sg >> 3) & 15, z = (sg >> 7) & 15, t = (sg >> 11) & 15;
        const int r = (t + z + y) & 1;           // OUT_PARITY = 0
        int dx = 0;
        if (cc == 6) dx =  (r == 1);             // X fwd hop only where mask_f
        if (cc == 7) dx = -(r == 0);             // X bwd hop only where mask_b
        const int nt = (t + dt) & 15, nz = (z + dz) & 15,
                  ny = (y + dy) & 15, nx = (x + dx) & 7;
        const int n = ((nt * 16 + nz) * 16 + ny) * 8 + nx;
        const int a = n * 12 + jj;
        tr[k]  = psi_re[a];
        ti[k]  = psi_im[a];
        dst[k] = s * VSTRIDE + cc * 12 + jj;
    }
    #pragma unroll
    for (int k = 0; k < 8; ++k) {
        ((float*)vre)[dst[k]] = tr[k];
        ((float*)vim)[dst[k]] = ti[k];
    }
    __syncthreads();

    // ---- compute: thread = (site scb, row jj), depth-2 pipelined K stream ----
    const int s      = scb;
    const int i      = jj;
    const int site   = site0 + s;
    const int rowoff = site * 144 + i * 12;      // floats; 48B units -> float4 aligned

    const float pr_c = psi_re[site * 12 + i];    // coalesced: block*192 + tid
    const float pi_c = psi_im[site * 12 + i];
    float o_re = DIAG * pr_c;
    float o_im = DIAG * pi_c;

    #define KR(c) ((const float4*)((((c) & 1) ? K_bwd_re : K_fwd_re) + ((c) >> 1) * MU_STRIDE + rowoff))
    #define KI(c) ((const float4*)((((c) & 1) ? K_bwd_im : K_fwd_im) + ((c) >> 1) * MU_STRIDE + rowoff))

    float4 cr0 = KR(0)[0], cr1 = KR(0)[1], cr2 = KR(0)[2];
    float4 ci0 = KI(0)[0], ci1 = KI(0)[1], ci2 = KI(0)[2];

    #pragma unroll
    for (int c = 0; c < 8; ++c) {
        float4 nr0, nr1, nr2, ni0, ni1, ni2;
        if (c < 7) {                              // compile-time under full unroll
            nr0 = KR(c + 1)[0]; nr1 = KR(c + 1)[1]; nr2 = KR(c + 1)[2];
            ni0 = KI(c + 1)[0]; ni1 = KI(c + 1)[1]; ni2 = KI(c + 1)[2];
        }
        const float4* v4r = (const float4*)&vre[s][c * 12];   // 48B aligned
        const float4* v4i = (const float4*)&vim[s][c * 12];
        const float4 vr0 = v4r[0], vr1 = v4r[1], vr2 = v4r[2];
        const float4 vi0 = v4i[0], vi1 = v4i[1], vi2 = v4i[2];
        float sr = 0.f, si = 0.f;
        cdot4(cr0, ci0, vr0, vi0, sr, si);
        cdot4(cr1, ci1, vr1, vi1, sr, si);
        cdot4(cr2, ci2, vr2, vi2, sr, si);
        o_re -= 0.5f * sr;
        o_im -= 0.5f * si;
        if (c < 7) { cr0 = nr0; cr1 = nr1; cr2 = nr2; ci0 = ni0; ci1 = ni1; ci2 = ni2; }
    }

    out_re[site * 12 + i] = o_re;
    out_im[site * 12 + i] = o_im;
}

extern "C" void kernel_launch(void* const* d_in, const int* in_sizes, int n_in,
                              void* d_out, int out_size, void* d_ws, size_t ws_size,
                              hipStream_t stream) {
    const float* psi_re   = (const float*)d_in[0];
    const float* psi_im   = (const float*)d_in[1];
    const float* K_fwd_re = (const float*)d_in[2];
    const float* K_fwd_im = (const float*)d_in[3];
    const float* K_bwd_re = (const float*)d_in[4];
    const float* K_bwd_im = (const float*)d_in[5];
    float* out_re = (float*)d_out;
    float* out_im = out_re + (out_size / 2);     // NSITES*12 = 393216

    hop_kernel<<<NSITES / SPB, THREADS, 0, stream>>>(
        psi_re, psi_im, K_fwd_re, K_fwd_im, K_bwd_re, K_bwd_im, out_re, out_im);
}

// Round 3
// 272.248 us; speedup vs baseline: 1.0402x; 1.0402x over previous
//
#include <hip/hip_runtime.h>

#define DD 12
#define NSITES 32768
#define SPB 16                    // sites per block
#define THREADS 192               // 3 waves; 192 = 16 sites x 12 rows
#define DIAG 4.5f
#define VSTRIDE 100               // psi LDS row stride (floats); 400B -> 4-bank site skew
#define MU_STRIDE (NSITES*144)
#define SLOT_BYTES 6144           // per wave per slot: re 3072B + im 3072B
#define WAVE_RING  (2*SLOT_BYTES) // 2-slot ring per wave

typedef __attribute__((address_space(3))) unsigned int       lds_u32_t;
typedef __attribute__((address_space(1))) const unsigned int gbl_u32_t;

// one wave-level DMA: 64 lanes x 16B -> contiguous 1KB global -> contiguous 1KB LDS
__device__ __forceinline__ void dma16(const float* gp, unsigned char* lp) {
    __builtin_amdgcn_global_load_lds((gbl_u32_t*)gp, (lds_u32_t*)lp, 16, 0, 0);
}

__device__ __forceinline__ void cdot4(const float4 kr, const float4 ki,
                                      const float4 vr, const float4 vi,
                                      float& sr, float& si) {
    sr = fmaf(kr.x, vr.x, sr); sr = fmaf(-ki.x, vi.x, sr);
    si = fmaf(kr.x, vi.x, si); si = fmaf(ki.x, vr.x, si);
    sr = fmaf(kr.y, vr.y, sr); sr = fmaf(-ki.y, vi.y, sr);
    si = fmaf(kr.y, vi.y, si); si = fmaf(ki.y, vr.y, si);
    sr = fmaf(kr.z, vr.z, sr); sr = fmaf(-ki.z, vi.z, sr);
    si = fmaf(kr.z, vi.z, si); si = fmaf(ki.z, vr.z, si);
    sr = fmaf(kr.w, vr.w, sr); sr = fmaf(-ki.w, vi.w, sr);
    si = fmaf(kr.w, vi.w, si); si = fmaf(ki.w, vr.w, si);
}

__global__ __launch_bounds__(THREADS, 2) void hop_kernel(
    const float* __restrict__ psi_re, const float* __restrict__ psi_im,
    const float* __restrict__ K_fwd_re, const float* __restrict__ K_fwd_im,
    const float* __restrict__ K_bwd_re, const float* __restrict__ K_bwd_im,
    float* __restrict__ out_re, float* __restrict__ out_im)
{
    __shared__ alignas(16) unsigned char kring[3 * WAVE_RING];   // 36864B
    __shared__ alignas(16) float vre[SPB][VSTRIDE];              // 6400B
    __shared__ alignas(16) float vim[SPB][VSTRIDE];              // 6400B

    const int tid   = threadIdx.x;
    const int site0 = blockIdx.x * SPB;
    const int wave  = tid >> 6;
    const int lane  = tid & 63;

    // ---- psi staging (pre-DMA; the ONLY barrier in the kernel) ----
    // thread stages one (combo cc, component jj) across 8 sites
    const int jj  = tid % 12;
    const int scb = tid / 12;
    const int cc  = scb & 7;
    const int sb  = scb >> 3;
    const int dt = (cc == 0) - (cc == 1);
    const int dz = (cc == 2) - (cc == 3);
    const int dy = (cc == 4) - (cc == 5);

    float tr[8], ti[8];
    int   dst[8];
    #pragma unroll
    for (int k = 0; k < 8; ++k) {
        const int s  = sb + 2 * k;
        const int sg = site0 + s;
        const int x = sg & 7, y = (sg >> 3) & 15, z = (sg >> 7) & 15, t = (sg >> 11) & 15;
        const int r = (t + z + y) & 1;                 // OUT_PARITY = 0
        int dx = 0;
        if (cc == 6) dx =  (r == 1);                   // X fwd where mask_f
        if (cc == 7) dx = -(r == 0);                   // X bwd where mask_b
        const int nt = (t + dt) & 15, nz = (z + dz) & 15,
                  ny = (y + dy) & 15, nx = (x + dx) & 7;
        const int n = ((nt * 16 + nz) * 16 + ny) * 8 + nx;
        tr[k]  = psi_re[n * 12 + jj];
        ti[k]  = psi_im[n * 12 + jj];
        dst[k] = s * VSTRIDE + cc * 12 + jj;
    }

    // center psi (coalesced; issued pre-barrier so the barrier drain covers it)
    const int s    = scb;          // compute-phase local site
    const int i    = jj;           // output row
    const int site = site0 + s;
    const float pr_c = psi_re[site * 12 + i];
    const float pi_c = psi_im[site * 12 + i];

    #pragma unroll
    for (int k = 0; k < 8; ++k) {
        ((float*)vre)[dst[k]] = tr[k];
        ((float*)vim)[dst[k]] = ti[k];
    }
    __syncthreads();               // drains all vmcnt; after this, vmcnt == 0

    float o_re = DIAG * pr_c;
    float o_im = DIAG * pi_c;

    // ---- barrier-free K stream: per-wave private DMA ring ----
    // wave w's 64 rows (tid 64w..64w+63) are a contiguous 3072B chunk per (c, re/im)
    unsigned char* wring = kring + wave * WAVE_RING;
    const int gw = site0 * 144 + wave * 768 + lane * 4;   // per-lane float index

    #define ISSUE(c) do { \
        const float* _kr = (((c) & 1) ? K_bwd_re : K_fwd_re) + ((c) >> 1) * MU_STRIDE + gw; \
        const float* _ki = (((c) & 1) ? K_bwd_im : K_fwd_im) + ((c) >> 1) * MU_STRIDE + gw; \
        unsigned char* _sp = wring + ((c) & 1) * SLOT_BYTES; \
        dma16(_kr,       _sp);                dma16(_ki,       _sp + 3072); \
        dma16(_kr + 256, _sp + 1024);         dma16(_ki + 256, _sp + 3072 + 1024); \
        dma16(_kr + 512, _sp + 2048);         dma16(_ki + 512, _sp + 3072 + 2048); \
    } while (0)

    ISSUE(0);                                   // outstanding: 6

    #pragma unroll
    for (int c = 0; c < 8; ++c) {
        __builtin_amdgcn_sched_barrier(0);      // pin: no hoisting DMA above prior reads
        if (c < 7) ISSUE(c + 1);                // outstanding: <=12
        if (c < 7) asm volatile("s_waitcnt vmcnt(6)" ::: "memory");   // slot c landed
        else       asm volatile("s_waitcnt vmcnt(0)" ::: "memory");
        const unsigned char* sp = wring + (c & 1) * SLOT_BYTES;
        const float4* kr4 = (const float4*)(sp + lane * 48);
        const float4* ki4 = (const float4*)(sp + 3072 + lane * 48);
        const float4* v4r = (const float4*)&vre[s][c * 12];
        const float4* v4i = (const float4*)&vim[s][c * 12];
        float sr = 0.f, si = 0.f;
        cdot4(kr4[0], ki4[0], v4r[0], v4i[0], sr, si);
        cdot4(kr4[1], ki4[1], v4r[1], v4i[1], sr, si);
        cdot4(kr4[2], ki4[2], v4r[2], v4i[2], sr, si);
        o_re -= 0.5f * sr;
        o_im -= 0.5f * si;
    }
    #undef ISSUE

    out_re[site * 12 + i] = o_re;               // block*192 + tid: fully coalesced
    out_im[site * 12 + i] = o_im;
}

extern "C" void kernel_launch(void* const* d_in, const int* in_sizes, int n_in,
                              void* d_out, int out_size, void* d_ws, size_t ws_size,
                              hipStream_t stream) {
    const float* psi_re   = (const float*)d_in[0];
    const float* psi_im   = (const float*)d_in[1];
    const float* K_fwd_re = (const float*)d_in[2];
    const float* K_fwd_im = (const float*)d_in[3];
    const float* K_bwd_re = (const float*)d_in[4];
    const float* K_bwd_im = (const float*)d_in[5];
    float* out_re = (float*)d_out;
    float* out_im = out_re + (out_size / 2);    // NSITES*12 = 393216

    hop_kernel<<<NSITES / SPB, THREADS, 0, stream>>>(
        psi_re, psi_im, K_fwd_re, K_fwd_im, K_bwd_re, K_bwd_im, out_re, out_im);
}